// Round 1
// baseline (549.125 us; speedup 1.0000x reference)
//
#include <hip/hip_runtime.h>
#include <stdint.h>

typedef unsigned short u16;

#define D_MODEL 2048
#define HEADS 16
#define HDIM 128
#define SEQ 2048
#define BATCH 2
#define NROWS (BATCH*SEQ)          // 4096
#define QKV_N (D_MODEL + 2*HDIM)   // 2304

typedef __attribute__((ext_vector_type(8))) short bf16x8;
typedef __attribute__((ext_vector_type(4))) float f32x4;

__device__ inline u16 f2bf(float f) {
  union { float f; uint32_t u; } v; v.f = f;
  uint32_t r = v.u + 0x7FFFu + ((v.u >> 16) & 1u);
  return (u16)(r >> 16);
}

// ---------------- elementwise fp32 -> bf16 ----------------
__global__ void cvt_bf16_4(const float* __restrict__ s, u16* __restrict__ d, int n4) {
  int i = blockIdx.x * 256 + threadIdx.x;
  if (i < n4) {
    float4 f = ((const float4*)s)[i];
    ushort4 u;
    u.x = f2bf(f.x); u.y = f2bf(f.y); u.z = f2bf(f.z); u.w = f2bf(f.w);
    ((ushort4*)d)[i] = u;
  }
}

// ---------------- transpose + convert: src fp32 [K=2048, N] -> dst bf16 rows [dstOff+n][k] ----------------
__global__ void transpose_cvt(const float* __restrict__ src, u16* __restrict__ dst,
                              int N, int dstOff) {
  __shared__ float t[32][33];
  const int k0 = blockIdx.y * 32, n0 = blockIdx.x * 32;
  const int tx = threadIdx.x, ty = threadIdx.y;  // 32 x 8
#pragma unroll
  for (int i = 0; i < 4; i++)
    t[ty + 8*i][tx] = src[(size_t)(k0 + ty + 8*i) * N + n0 + tx];
  __syncthreads();
#pragma unroll
  for (int i = 0; i < 4; i++)
    dst[(size_t)(dstOff + n0 + ty + 8*i) * D_MODEL + k0 + tx] = f2bf(t[tx][ty + 8*i]);
}

// ---------------- pack biases bq|bk|bv into [2304] fp32 ----------------
__global__ void pack_bias(const float* __restrict__ bq, const float* __restrict__ bk,
                          const float* __restrict__ bv, float* __restrict__ o) {
  int i = blockIdx.x * 256 + threadIdx.x;
  if (i < QKV_N)
    o[i] = (i < D_MODEL) ? bq[i] : ((i < D_MODEL + HDIM) ? bk[i - D_MODEL] : bv[i - D_MODEL - HDIM]);
}

// ---------------- bf16 GEMM, C = A[M,K] * BT[N,K]^T + bias ----------------
// 128x128 tile, BK=32, 4 waves, each wave 64x64 via 4x4 of 16x16x32 MFMA.
#define BM 128
#define BN 128
#define BK 32
#define LDK 40   // padded LDS row stride in u16 (80B -> conflict-free b128 reads)

__global__ __launch_bounds__(256) void gemm_bt(
    const u16* __restrict__ A, const u16* __restrict__ BT,
    const float* __restrict__ bias,
    u16* __restrict__ Cb, float* __restrict__ Cf,
    u16* __restrict__ vT,
    int M, int N, int K, int tilesN) {
  __shared__ __align__(16) u16 sA[BM * LDK];
  __shared__ __align__(16) u16 sB[BN * LDK];
  const int tid = threadIdx.x;
  const int wave = tid >> 6, lane = tid & 63;
  const int bm = blockIdx.x / tilesN, bn = blockIdx.x % tilesN;
  const int m0 = bm * BM, n0 = bn * BN;
  const int wm = (wave & 1) * 64, wn = (wave >> 1) * 64;
  const int l16 = lane & 15, kq = (lane >> 4) * 8;

  f32x4 acc[4][4] = {};

  const int r0 = tid >> 2, col0 = (tid & 3) * 8;        // chunk tid
  const int r1 = (tid + 256) >> 2, col1 = col0;          // chunk tid+256 (same col pattern)

  for (int k0 = 0; k0 < K; k0 += BK) {
    __syncthreads();
    *(uint4*)&sA[r0 * LDK + col0] = *(const uint4*)&A[(size_t)(m0 + r0) * K + k0 + col0];
    *(uint4*)&sA[r1 * LDK + col1] = *(const uint4*)&A[(size_t)(m0 + r1) * K + k0 + col1];
    *(uint4*)&sB[r0 * LDK + col0] = *(const uint4*)&BT[(size_t)(n0 + r0) * K + k0 + col0];
    *(uint4*)&sB[r1 * LDK + col1] = *(const uint4*)&BT[(size_t)(n0 + r1) * K + k0 + col1];
    __syncthreads();
    bf16x8 af[4], bfr[4];
#pragma unroll
    for (int mb = 0; mb < 4; ++mb) af[mb]  = *(const bf16x8*)&sA[(wm + mb*16 + l16) * LDK + kq];
#pragma unroll
    for (int nb = 0; nb < 4; ++nb) bfr[nb] = *(const bf16x8*)&sB[(wn + nb*16 + l16) * LDK + kq];
#pragma unroll
    for (int mb = 0; mb < 4; ++mb)
#pragma unroll
      for (int nb = 0; nb < 4; ++nb)
        acc[mb][nb] = __builtin_amdgcn_mfma_f32_16x16x32_bf16(af[mb], bfr[nb], acc[mb][nb], 0, 0, 0);
  }

  // epilogue: C/D layout col=lane&15, row=(lane>>4)*4+r  [verified m89/m91]
#pragma unroll
  for (int mb = 0; mb < 4; ++mb) {
#pragma unroll
    for (int nb = 0; nb < 4; ++nb) {
      const int gn = n0 + wn + nb * 16 + l16;
      const float bb = bias ? bias[gn] : 0.0f;
#pragma unroll
      for (int r = 0; r < 4; ++r) {
        const int gm = m0 + wm + mb * 16 + (lane >> 4) * 4 + r;
        const float v = acc[mb][nb][r] + bb;
        if (Cf) {
          Cf[(size_t)gm * N + gn] = v;
        } else {
          const u16 u = f2bf(v);
          Cb[(size_t)gm * N + gn] = u;
          if (vT && gn >= D_MODEL + HDIM) {  // also write V^T [b][d][s]
            const int bi = gm >> 11, si = gm & 2047;
            vT[((size_t)bi * HDIM + (gn - D_MODEL - HDIM)) * SEQ + si] = u;
          }
        }
      }
    }
  }
}

// ---------------- flash-style MQA attention ----------------
// WG = 4 waves; 64 Q rows per WG (16 per wave); 64-key tiles; online softmax.
__global__ __launch_bounds__(256) void mqa_attn(
    const u16* __restrict__ qkv, const u16* __restrict__ vT, u16* __restrict__ ctx) {
  __shared__ __align__(16) u16 sK[64 * 136];   // [sk][d]  d-pad 128->136
  __shared__ __align__(16) u16 sV[128 * 72];   // [d][sk]  sk-pad 64->72
  __shared__ __align__(16) u16 sP[4 * 16 * 72];// per-wave P [q][sk]
  const int tid = threadIdx.x, wave = tid >> 6, lane = tid & 63;
  const int qt = blockIdx.x & 31;
  const int h  = (blockIdx.x >> 5) & 15;
  const int b  = blockIdx.x >> 9;
  const int bS = b * SEQ;
  const int q0 = qt * 64;
  const int l16 = lane & 15, quad = lane >> 4;

  // stage Q tile into sK, read A-frags, then reuse sK for K tiles
#pragma unroll
  for (int j = 0; j < 4; j++) {
    const int c = j * 256 + tid;
    const int r = c >> 4, cs = c & 15;
    *(uint4*)&sK[r * 136 + cs * 8] =
        *(const uint4*)&qkv[(size_t)(bS + q0 + r) * QKV_N + h * HDIM + cs * 8];
  }
  __syncthreads();
  bf16x8 qf[4];
#pragma unroll
  for (int kc = 0; kc < 4; kc++)
    qf[kc] = *(const bf16x8*)&sK[(wave * 16 + l16) * 136 + kc * 32 + quad * 8];

  f32x4 o[8] = {};
  float mrow[4] = {-1e30f, -1e30f, -1e30f, -1e30f};
  float lrow[4] = {0.f, 0.f, 0.f, 0.f};
  const float sc2 = 0.08838834764831845f * 1.4426950408889634f;  // 1/sqrt(128) * log2(e)

  for (int t = 0; t < SEQ / 64; ++t) {
    const int sk0 = t * 64;
    __syncthreads();  // waves done with previous sK/sV/qf reads
#pragma unroll
    for (int j = 0; j < 4; j++) {
      const int c = j * 256 + tid;
      const int r = c >> 4, cs = c & 15;
      *(uint4*)&sK[r * 136 + cs * 8] =
          *(const uint4*)&qkv[(size_t)(bS + sk0 + r) * QKV_N + D_MODEL + cs * 8];
    }
#pragma unroll
    for (int j = 0; j < 4; j++) {
      const int c = j * 256 + tid;
      const int d = c >> 3, cs = c & 7;
      *(uint4*)&sV[d * 72 + cs * 8] =
          *(const uint4*)&vT[((size_t)b * HDIM + d) * SEQ + sk0 + cs * 8];
    }
    __syncthreads();

    // S = Q K^T (raw scores)
    f32x4 sc[4];
#pragma unroll
    for (int nb = 0; nb < 4; nb++) {
      f32x4 a = {0.f, 0.f, 0.f, 0.f};
#pragma unroll
      for (int kc = 0; kc < 4; kc++) {
        bf16x8 kf = *(const bf16x8*)&sK[(nb * 16 + l16) * 136 + kc * 32 + quad * 8];
        a = __builtin_amdgcn_mfma_f32_16x16x32_bf16(qf[kc], kf, a, 0, 0, 0);
      }
      sc[nb] = a;
    }

    // online softmax (m/l tracked in log2-scaled units)
    float tmax[4];
#pragma unroll
    for (int r = 0; r < 4; r++)
      tmax[r] = fmaxf(fmaxf(sc[0][r], sc[1][r]), fmaxf(sc[2][r], sc[3][r]));
#pragma unroll
    for (int off = 8; off >= 1; off >>= 1)
#pragma unroll
      for (int r = 0; r < 4; r++) tmax[r] = fmaxf(tmax[r], __shfl_xor(tmax[r], off, 64));

    float mnew[4], alpha[4], tsum[4];
#pragma unroll
    for (int r = 0; r < 4; r++) {
      mnew[r] = fmaxf(mrow[r], tmax[r] * sc2);
      alpha[r] = exp2f(mrow[r] - mnew[r]);
      mrow[r] = mnew[r];
      tsum[r] = 0.f;
    }
#pragma unroll
    for (int nb = 0; nb < 4; nb++)
#pragma unroll
      for (int r = 0; r < 4; r++) {
        const float p = exp2f(sc[nb][r] * sc2 - mnew[r]);
        tsum[r] += p;
        sP[(wave * 16 + quad * 4 + r) * 72 + nb * 16 + l16] = f2bf(p);
      }
#pragma unroll
    for (int off = 8; off >= 1; off >>= 1)
#pragma unroll
      for (int r = 0; r < 4; r++) tsum[r] += __shfl_xor(tsum[r], off, 64);
#pragma unroll
    for (int r = 0; r < 4; r++) lrow[r] = lrow[r] * alpha[r] + tsum[r];
#pragma unroll
    for (int nb = 0; nb < 8; nb++)
#pragma unroll
      for (int r = 0; r < 4; r++) o[nb][r] *= alpha[r];

    __syncthreads();  // sP visible (cross-lane within wave; cheap safety barrier)

    // PV: P[16,64] @ V[64,128]
    bf16x8 pf[2];
#pragma unroll
    for (int kc = 0; kc < 2; kc++)
      pf[kc] = *(const bf16x8*)&sP[(wave * 16 + l16) * 72 + kc * 32 + quad * 8];
#pragma unroll
    for (int nb = 0; nb < 8; nb++)
#pragma unroll
      for (int kc = 0; kc < 2; kc++) {
        bf16x8 vf = *(const bf16x8*)&sV[(nb * 16 + l16) * 72 + kc * 32 + quad * 8];
        o[nb] = __builtin_amdgcn_mfma_f32_16x16x32_bf16(pf[kc], vf, o[nb], 0, 0, 0);
      }
  }

  float invl[4];
#pragma unroll
  for (int r = 0; r < 4; r++) invl[r] = 1.0f / lrow[r];
#pragma unroll
  for (int nb = 0; nb < 8; nb++)
#pragma unroll
    for (int r = 0; r < 4; r++) {
      const int gq = q0 + wave * 16 + quad * 4 + r;
      const int gd = h * HDIM + nb * 16 + l16;
      ctx[(size_t)(bS + gq) * D_MODEL + gd] = f2bf(o[nb][r] * invl[r]);
    }
}

// ---------------- launch ----------------
extern "C" void kernel_launch(void* const* d_in, const int* in_sizes, int n_in,
                              void* d_out, int out_size, void* d_ws, size_t ws_size,
                              hipStream_t stream) {
  const float* x  = (const float*)d_in[0];
  const float* wq = (const float*)d_in[1];
  const float* bq = (const float*)d_in[2];
  const float* wk = (const float*)d_in[3];
  const float* bk = (const float*)d_in[4];
  const float* wv = (const float*)d_in[5];
  const float* bv = (const float*)d_in[6];
  const float* wo = (const float*)d_in[7];
  const float* bo = (const float*)d_in[8];
  float* out = (float*)d_out;
  char* ws = (char*)d_ws;

  // workspace layout (bytes), all 16B-aligned
  u16*   xb    = (u16*)(ws + 0);          // [4096,2048] bf16   16777216
  u16*   wqkvT = (u16*)(ws + 16777216);   // [2304,2048] bf16    9437184
  u16*   woT   = (u16*)(ws + 26214400);   // [2048,2048] bf16    8388608
  u16*   qkv   = (u16*)(ws + 34603008);   // [4096,2304] bf16   18874368
  u16*   vT    = (u16*)(ws + 53477376);   // [2,128,2048] bf16   1048576
  u16*   ctx   = (u16*)(ws + 54525952);   // [4096,2048] bf16   16777216
  float* biasq = (float*)(ws + 71303168); // [2304] f32

  cvt_bf16_4<<<8192, 256, 0, stream>>>(x, xb, (NROWS * D_MODEL) / 4);
  dim3 tb(32, 8);
  transpose_cvt<<<dim3(64, 64), tb, 0, stream>>>(wq, wqkvT, 2048, 0);
  transpose_cvt<<<dim3(4, 64),  tb, 0, stream>>>(wk, wqkvT, 128, 2048);
  transpose_cvt<<<dim3(4, 64),  tb, 0, stream>>>(wv, wqkvT, 128, 2176);
  transpose_cvt<<<dim3(64, 64), tb, 0, stream>>>(wo, woT, 2048, 0);
  pack_bias<<<9, 256, 0, stream>>>(bq, bk, bv, biasq);

  gemm_bt<<<32 * 18, 256, 0, stream>>>(xb, wqkvT, biasq, qkv, nullptr, vT,
                                       NROWS, QKV_N, D_MODEL, 18);
  mqa_attn<<<BATCH * HEADS * (SEQ / 64), 256, 0, stream>>>(qkv, vT, ctx);
  gemm_bt<<<32 * 16, 256, 0, stream>>>(ctx, woT, bo, nullptr, out, nullptr,
                                       NROWS, D_MODEL, D_MODEL, 16);
}